// Round 6
// baseline (138.479 us; speedup 1.0000x reference)
//
#include <hip/hip_runtime.h>
#include <math.h>

#define E_TOTAL  200000
#define NNODES   12500
#define OUT_ELEM 800000          // 12500 * 64
#define NTILE    (E_TOTAL / 64)  // 3125
#define PAD      64              // max tracked degree (Poisson(16): P(>64) ~ 1e-20)

typedef float    f32x4 __attribute__((ext_vector_type(4)));
typedef _Float16 f16x8 __attribute__((ext_vector_type(8)));
typedef _Float16 f16x4 __attribute__((ext_vector_type(4)));
typedef _Float16 f16x2 __attribute__((ext_vector_type(2)));

union AF { f16x8 f; f16x2 h2[4]; };

// ---------------- workspace layout (bytes) ----------------
// edge_out : f16  NNODES*PAD*64   (dst-grouped rows: node n owns rows [n*PAD, n*PAD+cnt[n]))
// cnt      : int  NNODES
// bfrag    : f16  36*64*8         (alpha-scaled, MFMA B-layout)
static const size_t OFF_CNT    = (size_t)NNODES * PAD * 64 * 2;         // 102,400,000
static const size_t OFF_BFRAG  = (OFF_CNT + (size_t)NNODES * 4 + 15) & ~(size_t)15;
static const size_t WS_NEEDED  = OFF_BFRAG + (size_t)36 * 64 * 8 * 2;

// ================= prep: cnt=0 + swizzled f16 B-fragments =================
// B-frag layout for mfma_f32_16x16x32_f16: lane holds B[k=quad*8+j][n=lane&15].
// slot = br*9+kb; kb<8: ku = kb*32+quad*8+j -> w2[ku>>4][br*256+(ku&15)*16+n]
//                 kb==8: bias block (loc<16 -> b2, else 0). alpha folded in.
__global__ void k_prep(const float* __restrict__ w2, const float* __restrict__ b2,
                       int* __restrict__ cnt, _Float16* __restrict__ bfrag) {
    const int g = blockIdx.x * 256 + threadIdx.x;
    if (g < NNODES) cnt[g] = 0;
    if (g < 36 * 64) {
        const int slot = g >> 6, lane = g & 63;
        const int br = slot / 9, kb = slot - br * 9;
        const int quad = lane >> 4, n = lane & 15;
        const float alpha = 0.17677669529663687f;   // 1/sqrt(32)
        _Float16* dst = bfrag + (size_t)g * 8;
        #pragma unroll
        for (int j = 0; j < 8; ++j) {
            float v;
            if (kb < 8) {
                const int ku = kb * 32 + quad * 8 + j;
                v = w2[(ku >> 4) * 1024 + br * 256 + (ku & 15) * 16 + n];
            } else {
                const int loc = quad * 8 + j;
                v = (loc < 16) ? b2[br * 256 + loc * 16 + n] : 0.0f;
            }
            dst[j] = (_Float16)(alpha * v);
        }
    }
}

// ================= fused conv: BARRIER-FREE, one wave = 16 edges ============
// ROUND-6 RESTRUCTURE. Rounds 2-5 proved the per-wave latency chain can't be
// shortened with ILP (LDS staging / hoist / asm pins all ~48-62us), and at
// 60KB LDS there were only 2 waves/SIMD to hide it with TLP. Fix: each wave
// owns 16 edges END-TO-END, so all LDS slices are wave-private:
//   * ZERO __syncthreads (intra-wave ds_write->ds_read is in-order);
//   * sh_row / sh_y replaced by __shfl (source lane = edge idx < 16);
//   * bfrag read from global (36KB, L2-resident, shared by all 12.5k waves)
//     instead of an LDS copy -> LDS 22.8KB;
//   * __launch_bounds__(256,4): 4 blocks/CU, 4 waves/SIMD, all independent.
// Per-wave roles by hi=lane>>4, m=lane&15 (edge):
//   phase1a: (m=edge, hi=kq)  phase1b: (m=edge, hi=pp)  K-loop: (m=col, hi=quad)
// Six GEMMs C(16e x 16w) = A(16 x 288) @ B(288 x 16); kb=8 = bias block.
// A rank-1: A[e][quad*8+j] = h[e][2kb+qh] * s[e][ql*8+j]. C/D: row(edge) =
// quad*4+r, col(w) = lane&15. alpha folded into B.
__global__ __launch_bounds__(256, 4) void k_conv(
        const float* __restrict__ node_attr,
        const int*   __restrict__ edge_index,
        const float* __restrict__ edge_attr,
        const float* __restrict__ edge_sh,
        const float* __restrict__ w1,
        const float* __restrict__ b1,
        const f16x8* __restrict__ bfrag,
        int* __restrict__ cnt,
        _Float16* __restrict__ edge_out)
{
    const int t = threadIdx.x;
    const int wv = t >> 6, lane = t & 63;
    const int m = lane & 15, hi = lane >> 4;

    __shared__ float    sh_h[4][16][17];            // 4352 B (wave-private slices)
    __shared__ _Float16 sh_s[4][6][16][24];         // 18432 B (wave-private slices)

    const int ebw = blockIdx.x * 64 + wv * 16;      // this wave's 16 edges
    const float inv_sqrt3 = 0.57735026918962576f;

    // ---- slot-map atomic (lanes 0-15); result used only in the epilogue
    int myrow = 0;
    if (lane < 16) {
        const int e2 = ebw + lane;
        const int d = edge_index[E_TOTAL + e2];
        int slot = atomicAdd(&cnt[d], 1);
        if (slot >= PAD) slot = PAD - 1;            // memory-safety clamp (never hit)
        myrow = d * PAD + slot;
    }

    const int e = ebw + m;

    // ---- phase 1b operands (yv stays live until the epilogue shfl)
    const int src = edge_index[e];
    const float4 yv = *(const float4*)(edge_sh + (size_t)e * 4);
    const int u0 = hi * 4;
    const float* xp = node_attr + (size_t)src * 64;
    const float4 x0v = *(const float4*)(xp + u0);
    float4 x1q[3];
    #pragma unroll
    for (int q = 0; q < 3; ++q) x1q[q] = *(const float4*)(xp + 16 + u0 * 3 + q * 4);

    // ---- phase 1a: h = silu(edge_attr @ w1 + b1)   (lane = (edge m, kq=hi))
    {
        const float* ea = edge_attr + (size_t)e * 16;
        float ear[16];
        #pragma unroll
        for (int dq = 0; dq < 4; ++dq) {
            float4 v = *(const float4*)(ea + dq * 4);
            ear[dq * 4 + 0] = v.x; ear[dq * 4 + 1] = v.y;
            ear[dq * 4 + 2] = v.z; ear[dq * 4 + 3] = v.w;
        }
        float4 acc = *(const float4*)(b1 + hi * 4);
        #pragma unroll
        for (int d = 0; d < 16; ++d) {
            float4 wr = *(const float4*)(w1 + d * 16 + hi * 4);
            acc.x += ear[d] * wr.x; acc.y += ear[d] * wr.y;
            acc.z += ear[d] * wr.z; acc.w += ear[d] * wr.w;
        }
        sh_h[wv][m][hi * 4 + 0] = acc.x / (1.0f + __expf(-acc.x));
        sh_h[wv][m][hi * 4 + 1] = acc.y / (1.0f + __expf(-acc.y));
        sh_h[wv][m][hi * 4 + 2] = acc.z / (1.0f + __expf(-acc.z));
        sh_h[wv][m][hi * 4 + 3] = acc.w / (1.0f + __expf(-acc.w));
    }

    // ---- phase 1b: stage s-vectors (f16)   (lane = (edge m, pp=hi))
    {
        const float x0p[4] = {x0v.x, x0v.y, x0v.z, x0v.w};
        const float x1p[12] = {x1q[0].x, x1q[0].y, x1q[0].z, x1q[0].w,
                               x1q[1].x, x1q[1].y, x1q[1].z, x1q[1].w,
                               x1q[2].x, x1q[2].y, x1q[2].z, x1q[2].w};
        f16x4 s0h, s1h, x0h, ah, bh, ch;
        #pragma unroll
        for (int q = 0; q < 4; ++q) {
            const float xa = x1p[q * 3 + 0], xb = x1p[q * 3 + 1], xc = x1p[q * 3 + 2];
            s0h[q] = (_Float16)(x0p[q] * yv.x);
            s1h[q] = (_Float16)(inv_sqrt3 * (xa * yv.y + xb * yv.z + xc * yv.w));
            x0h[q] = (_Float16)x0p[q];
            ah[q]  = (_Float16)xa;
            bh[q]  = (_Float16)xb;
            ch[q]  = (_Float16)xc;
        }
        *(f16x4*)&sh_s[wv][0][m][u0] = s0h;
        *(f16x4*)&sh_s[wv][1][m][u0] = s1h;
        *(f16x4*)&sh_s[wv][2][m][u0] = x0h;
        *(f16x4*)&sh_s[wv][3][m][u0] = ah;
        *(f16x4*)&sh_s[wv][4][m][u0] = bh;
        *(f16x4*)&sh_s[wv][5][m][u0] = ch;
    }

    // ---- phase 2: MFMA K-loop (lane = (col m, quad=hi)); NO BARRIER —
    // reads only this wave's own LDS slices (in-order LDS pipe).
    const int qh = hi >> 1, ql = hi & 1;

    AF svh[6];
    #pragma unroll
    for (int b = 0; b < 6; ++b)
        svh[b].f = *(const f16x8*)&sh_s[wv][b][m][ql * 8];
    float hreg[8];
    #pragma unroll
    for (int kb = 0; kb < 8; ++kb) hreg[kb] = sh_h[wv][m][2 * kb + qh];

    f32x4 acc0  = {0.f, 0.f, 0.f, 0.f};
    f32x4 acc2  = {0.f, 0.f, 0.f, 0.f};
    f32x4 acc3a = {0.f, 0.f, 0.f, 0.f};
    f32x4 acc3b = {0.f, 0.f, 0.f, 0.f};
    f32x4 acc3c = {0.f, 0.f, 0.f, 0.f};

    #pragma unroll
    for (int kb = 0; kb < 9; ++kb) {
        const f16x8 B0 = bfrag[(0 * 9 + kb) * 64 + lane];   // L2-resident broadcast
        const f16x8 B1 = bfrag[(1 * 9 + kb) * 64 + lane];
        const f16x8 B2 = bfrag[(2 * 9 + kb) * 64 + lane];
        const f16x8 B3 = bfrag[(3 * 9 + kb) * 64 + lane];
        const float selF = (kb < 8) ? hreg[kb] : ((hi < 2) ? 1.0f : 0.0f);
        const _Float16 sh1 = (_Float16)selF;
        const f16x2 sel2 = (f16x2){sh1, sh1};
        AF A[6];
        #pragma unroll
        for (int b = 0; b < 6; ++b)
            #pragma unroll
            for (int p = 0; p < 4; ++p)
                A[b].h2[p] = sel2 * svh[b].h2[p];    // v_pk_mul_f16
        acc0  = __builtin_amdgcn_mfma_f32_16x16x32_f16(A[0].f, B0, acc0, 0, 0, 0);
        acc0  = __builtin_amdgcn_mfma_f32_16x16x32_f16(A[1].f, B1, acc0, 0, 0, 0);
        acc2  = __builtin_amdgcn_mfma_f32_16x16x32_f16(A[2].f, B2, acc2, 0, 0, 0);
        acc3a = __builtin_amdgcn_mfma_f32_16x16x32_f16(A[3].f, B3, acc3a, 0, 0, 0);
        acc3b = __builtin_amdgcn_mfma_f32_16x16x32_f16(A[4].f, B3, acc3b, 0, 0, 0);
        acc3c = __builtin_amdgcn_mfma_f32_16x16x32_f16(A[5].f, B3, acc3c, 0, 0, 0);
    }

    // ---- epilogue: rows + y via __shfl from lane el (<16); no LDS, no barrier
    #pragma unroll
    for (int r = 0; r < 4; ++r) {
        const int el = hi * 4 + r;                  // edge within this wave's tile
        const int   row = __shfl(myrow, el);
        const float y0s = __shfl(yv.x, el);
        const float y1s = __shfl(yv.y, el);
        const float y2s = __shfl(yv.z, el);
        const float y3s = __shfl(yv.w, el);
        const float t2v = acc2[r];
        const float o0 = acc0[r];
        const float oa = y1s * t2v + y0s * acc3a[r];
        const float ob = y2s * t2v + y0s * acc3b[r];
        const float oc = y3s * t2v + y0s * acc3c[r];
        f16x4 pk = {(_Float16)o0, (_Float16)oa, (_Float16)ob, (_Float16)oc};
        *(f16x4*)(edge_out + (size_t)row * 64 + m * 4) = pk;
    }
}

// ================= gather (segment mean): CONTIGUOUS per-node rows =================
// One wave per node. Node n's edge rows live at [n*PAD, n*PAD+c) — sequential.
// Lane l loads f16x8 (16 B) covering 8 rows per wave-instruction (1 KB/instr);
// column sums reduced across row-cosets via 3 shfl_xor steps; 256 B LDS bounce
// resolves the in-row output permutation.
__global__ __launch_bounds__(256) void k_gather(const _Float16* __restrict__ edge_out,
                                                const int* __restrict__ cnt,
                                                float* __restrict__ out) {
    __shared__ float sh_sum[4][64];
    const int t = threadIdx.x;
    const int lane = t & 63;
    const int wv = t >> 6;
    const int n = blockIdx.x * 4 + wv;
    // in-row permutation: elem<16 -> row[elem*4]; elem=16+w*3+i -> row[w*4+1+i]
    int pe;
    if (lane < 16) pe = lane * 4;
    else { const int idx = lane - 16; const int w = idx / 3; pe = w * 4 + 1 + (idx - w * 3); }
    int c = cnt[n];
    if (c > PAD) c = PAD;
    const int ng = (c + 7) >> 3;                    // groups of 8 rows
    const f16x8* base = (const f16x8*)(edge_out + (size_t)n * PAD * 64);
    const int rsub = lane >> 3;                     // this lane's row within a group
    float acc[8] = {0.f, 0.f, 0.f, 0.f, 0.f, 0.f, 0.f, 0.f};
    for (int g = 0; g < ng; ++g) {
        const f16x8 v = base[g * 64 + lane];        // 64 lanes x 16 B = 8 full rows
        const int r = g * 8 + rsub;
        #pragma unroll
        for (int i = 0; i < 8; ++i)
            acc[i] += (r < c) ? (float)v[i] : 0.0f; // cndmask masks poison rows
    }
    // reduce across the 8 lanes holding the same columns (l, l^8, l^16, l^32)
    #pragma unroll
    for (int i = 0; i < 8; ++i) {
        acc[i] += __shfl_xor(acc[i], 8);
        acc[i] += __shfl_xor(acc[i], 16);
        acc[i] += __shfl_xor(acc[i], 32);
    }
    if (lane < 8) {
        #pragma unroll
        for (int i = 0; i < 8; ++i) sh_sum[wv][lane * 8 + i] = acc[i];
    }
    __syncthreads();
    const float s = sh_sum[wv][pe];
    out[n * 64 + lane] = s / (c > 0 ? (float)c : 1.0f);
}

// ================= fallback path (round-1 atomic fp32, proven) =================
__global__ void k_zero_f(float* __restrict__ out, float* __restrict__ counts) {
    int i = blockIdx.x * 256 + threadIdx.x;
    if (i < OUT_ELEM) out[i] = 0.0f;
    if (i < NNODES)   counts[i] = 0.0f;
}

#define EPB 80
#define NE  8
__global__ __launch_bounds__(256) void k_conv_atomic(
        const float* __restrict__ node_attr,
        const int*   __restrict__ edge_index,
        const float* __restrict__ edge_attr,
        const float* __restrict__ edge_sh,
        const float* __restrict__ w1,
        const float* __restrict__ b1,
        const float* __restrict__ w2,
        const float* __restrict__ b2,
        float* __restrict__ out,
        float* __restrict__ counts)
{
    const int thr   = threadIdx.x;
    const int lane  = thr & 63;
    const int wv    = thr >> 6;
    const int u     = lane >> 2;
    const int wbase = (lane & 3) * 4;

    float4 w2r[16];
    #pragma unroll
    for (int k = 0; k < 16; ++k)
        w2r[k] = *(const float4*)(w2 + k * 1024 + thr * 4);
    const float4 b2r = *(const float4*)(b2 + thr * 4);

    __shared__ __align__(16) float sh_h[NE][16];
    __shared__ float sh_s0[NE][16];
    __shared__ float sh_s1[NE][16];
    __shared__ float sh_x0[NE][16];
    __shared__ float sh_x1[NE][16][3];
    __shared__ float sh_y0[NE];
    __shared__ float sh_y1[NE][3];
    __shared__ int   sh_dst[NE];

    const float alpha     = 0.17677669529663687f;
    const float inv_sqrt3 = 0.57735026918962576f;
    const int e0 = blockIdx.x * EPB;

    for (int batch = 0; batch < EPB / NE; ++batch) {
        const int ebase = e0 + batch * NE;
        if (thr < 128) {
            const int le = thr >> 4, k = thr & 15;
            const int e = ebase + le;
            float acc = b1[k];
            const float* ea = edge_attr + (size_t)e * 16;
            #pragma unroll
            for (int d = 0; d < 16; ++d) acc += ea[d] * w1[d * 16 + k];
            sh_h[le][k] = acc / (1.0f + __expf(-acc));
            if (k == 0) sh_dst[le] = edge_index[E_TOTAL + e];
        } else {
            const int le = (thr - 128) >> 4, uu = thr & 15;
            const int e = ebase + le;
            const int src = edge_index[e];
            const float y0  = edge_sh[e * 4 + 0];
            const float y1a = edge_sh[e * 4 + 1];
            const float y1b = edge_sh[e * 4 + 2];
            const float y1c = edge_sh[e * 4 + 3];
            const float* xp = node_attr + (size_t)src * 64;
            const float x0v = xp[uu];
            const float xa = xp[16 + uu * 3 + 0];
            const float xb = xp[16 + uu * 3 + 1];
            const float xc = xp[16 + uu * 3 + 2];
            sh_x0[le][uu] = x0v;
            sh_x1[le][uu][0] = xa; sh_x1[le][uu][1] = xb; sh_x1[le][uu][2] = xc;
            sh_s0[le][uu] = x0v * y0;
            sh_s1[le][uu] = inv_sqrt3 * (xa * y1a + xb * y1b + xc * y1c);
            if (uu == 0) {
                sh_y0[le] = y0;
                sh_y1[le][0] = y1a; sh_y1[le][1] = y1b; sh_y1[le][2] = y1c;
            }
        }
        __syncthreads();

        for (int le = 0; le < NE; ++le) {
            float W0 = b2r.x, W1 = b2r.y, W2c = b2r.z, W3c = b2r.w;
            const float4* hv = (const float4*)sh_h[le];
            #pragma unroll
            for (int kk = 0; kk < 4; ++kk) {
                const float4 h4 = hv[kk];
                const int kb = kk * 4;
                W0  += h4.x * w2r[kb + 0].x; W1  += h4.x * w2r[kb + 0].y;
                W2c += h4.x * w2r[kb + 0].z; W3c += h4.x * w2r[kb + 0].w;
                W0  += h4.y * w2r[kb + 1].x; W1  += h4.y * w2r[kb + 1].y;
                W2c += h4.y * w2r[kb + 1].z; W3c += h4.y * w2r[kb + 1].w;
                W0  += h4.z * w2r[kb + 2].x; W1  += h4.z * w2r[kb + 2].y;
                W2c += h4.z * w2r[kb + 2].z; W3c += h4.z * w2r[kb + 2].w;
                W0  += h4.w * w2r[kb + 3].x; W1  += h4.w * w2r[kb + 3].y;
                W2c += h4.w * w2r[kb + 3].z; W3c += h4.w * w2r[kb + 3].w;
            }
            const int dst = sh_dst[le];
            float* op = out + (size_t)dst * 64;
            if (wv == 0 || wv == 1) {
                const float s = (wv == 0) ? sh_s0[le][u] : sh_s1[le][u];
                float v0 = s * W0, v1 = s * W1, v2 = s * W2c, v3 = s * W3c;
                #pragma unroll
                for (int off = 4; off <= 32; off <<= 1) {
                    v0 += __shfl_xor(v0, off); v1 += __shfl_xor(v1, off);
                    v2 += __shfl_xor(v2, off); v3 += __shfl_xor(v3, off);
                }
                if (lane < 4) {
                    atomicAdd(op + wbase + 0, alpha * v0);
                    atomicAdd(op + wbase + 1, alpha * v1);
                    atomicAdd(op + wbase + 2, alpha * v2);
                    atomicAdd(op + wbase + 3, alpha * v3);
                    if (wv == 0 && lane == 0) atomicAdd(&counts[dst], 1.0f);
                }
            } else if (wv == 2) {
                const float s = sh_x0[le][u];
                float v0 = s * W0, v1 = s * W1, v2 = s * W2c, v3 = s * W3c;
                #pragma unroll
                for (int off = 4; off <= 32; off <<= 1) {
                    v0 += __shfl_xor(v0, off); v1 += __shfl_xor(v1, off);
                    v2 += __shfl_xor(v2, off); v3 += __shfl_xor(v3, off);
                }
                if (lane < 4) {
                    const float ya = alpha * sh_y1[le][0];
                    const float yb = alpha * sh_y1[le][1];
                    const float yc = alpha * sh_y1[le][2];
                    float vv[4] = {v0, v1, v2, v3};
                    #pragma unroll
                    for (int q = 0; q < 4; ++q) {
                        float* qp = op + 16 + (wbase + q) * 3;
                        atomicAdd(qp + 0, vv[q] * ya);
                        atomicAdd(qp + 1, vv[q] * yb);
                        atomicAdd(qp + 2, vv[q] * yc);
                    }
                }
            } else {
                const float ay0 = alpha * sh_y0[le];
                #pragma unroll
                for (int i = 0; i < 3; ++i) {
                    const float s = sh_x1[le][u][i];
                    float v0 = s * W0, v1 = s * W1, v2 = s * W2c, v3 = s * W3c;
                    #pragma unroll
                    for (int off = 4; off <= 32; off <<= 1) {
                        v0 += __shfl_xor(v0, off); v1 += __shfl_xor(v1, off);
                        v2 += __shfl_xor(v2, off); v3 += __shfl_xor(v3, off);
                    }
                    if (lane < 4) {
                        atomicAdd(op + 16 + (wbase + 0) * 3 + i, ay0 * v0);
                        atomicAdd(op + 16 + (wbase + 1) * 3 + i, ay0 * v1);
                        atomicAdd(op + 16 + (wbase + 2) * 3 + i, ay0 * v2);
                        atomicAdd(op + 16 + (wbase + 3) * 3 + i, ay0 * v3);
                    }
                }
            }
        }
        __syncthreads();
    }
}

__global__ void k_div(float* __restrict__ out, const float* __restrict__ counts) {
    int i = blockIdx.x * 256 + threadIdx.x;
    if (i < OUT_ELEM) {
        float c = counts[i >> 6];
        out[i] *= 1.0f / fmaxf(c, 1.0f);
    }
}

// ================= launch =================
extern "C" void kernel_launch(void* const* d_in, const int* in_sizes, int n_in,
                              void* d_out, int out_size, void* d_ws, size_t ws_size,
                              hipStream_t stream) {
    const float* node_attr  = (const float*)d_in[0];
    const int*   edge_index = (const int*)d_in[1];
    const float* edge_attr  = (const float*)d_in[2];
    const float* edge_sh    = (const float*)d_in[3];
    const float* w1         = (const float*)d_in[4];
    const float* b1         = (const float*)d_in[5];
    const float* w2         = (const float*)d_in[6];
    const float* b2         = (const float*)d_in[7];
    float* out = (float*)d_out;

    if (ws_size >= WS_NEEDED) {
        char* ws = (char*)d_ws;
        _Float16* edge_out = (_Float16*)ws;
        int*      cnt      = (int*)(ws + OFF_CNT);
        _Float16* bfrag    = (_Float16*)(ws + OFF_BFRAG);

        k_prep<<<(NNODES + 255) / 256, 256, 0, stream>>>(w2, b2, cnt, bfrag);
        k_conv<<<NTILE, 256, 0, stream>>>(
            node_attr, edge_index, edge_attr, edge_sh, w1, b1,
            (const f16x8*)bfrag, cnt, edge_out);
        k_gather<<<NNODES / 4, 256, 0, stream>>>(edge_out, cnt, out);
    } else {
        float* counts = (float*)d_ws;
        k_zero_f<<<(OUT_ELEM + 255) / 256, 256, 0, stream>>>(out, counts);
        k_conv_atomic<<<E_TOTAL / EPB, 256, 0, stream>>>(
            node_attr, edge_index, edge_attr, edge_sh, w1, b1, w2, b2, out, counts);
        k_div<<<(OUT_ELEM + 255) / 256, 256, 0, stream>>>(out, counts);
    }
}

// Round 7
// 125.989 us; speedup vs baseline: 1.0991x; 1.0991x over previous
//
#include <hip/hip_runtime.h>
#include <math.h>

#define E_TOTAL  200000
#define NNODES   12500
#define OUT_ELEM 800000          // 12500 * 64
#define NTILE    (E_TOTAL / 64)  // 3125
#define NREP     4               // cnt replicas (cut same-line atomic serialization 4x)
#define RSLOT    32              // slots per replica: Poisson(4), P(>32) ~ 1e-11
#define PAD      (NREP * RSLOT)  // 128 pos slots per node

typedef float    f32x4 __attribute__((ext_vector_type(4)));
typedef _Float16 f16x8 __attribute__((ext_vector_type(8)));
typedef _Float16 f16x4 __attribute__((ext_vector_type(4)));
typedef _Float16 f16x2 __attribute__((ext_vector_type(2)));

union AF { f16x8 f; f16x2 h2[4]; };

// ---------------- workspace layout (bytes) ----------------
// edge_out : f16  E*64            (contiguous per-edge rows, alpha folded in)
// cnt      : int  NREP*NNODES     (replicated slot counters)
// pos      : int  NNODES*PAD      (slot map: node -> edge ids, replica-ranged)
// bfrag    : f16  36*64*8         (alpha-scaled, MFMA B-layout)
static const size_t OFF_CNT    = (size_t)E_TOTAL * 64 * 2;                    // 25,600,000
static const size_t OFF_POS    = OFF_CNT + (size_t)NREP * NNODES * 4;
static const size_t OFF_BFRAG  = (OFF_POS + (size_t)NNODES * PAD * 4 + 15) & ~(size_t)15;
static const size_t WS_NEEDED  = OFF_BFRAG + (size_t)36 * 64 * 8 * 2;

// ================= prep: cnt=0 + swizzled f16 B-fragments =================
// B-frag layout for mfma_f32_16x16x32_f16: lane holds B[k=quad*8+j][n=lane&15].
// slot = br*9+kb; kb<8: ku = kb*32+quad*8+j -> w2[ku>>4][br*256+(ku&15)*16+n]
//                 kb==8: bias block (loc<16 -> b2, else 0). alpha folded in.
__global__ void k_prep(const float* __restrict__ w2, const float* __restrict__ b2,
                       int* __restrict__ cnt, _Float16* __restrict__ bfrag) {
    const int g = blockIdx.x * 256 + threadIdx.x;
    if (g < NREP * NNODES) cnt[g] = 0;
    if (g < 36 * 64) {
        const int slot = g >> 6, lane = g & 63;
        const int br = slot / 9, kb = slot - br * 9;
        const int quad = lane >> 4, n = lane & 15;
        const float alpha = 0.17677669529663687f;   // 1/sqrt(32)
        _Float16* dst = bfrag + (size_t)g * 8;
        #pragma unroll
        for (int j = 0; j < 8; ++j) {
            float v;
            if (kb < 8) {
                const int ku = kb * 32 + quad * 8 + j;
                v = w2[(ku >> 4) * 1024 + br * 256 + (ku & 15) * 16 + n];
            } else {
                const int loc = quad * 8 + j;
                v = (loc < 16) ? b2[br * 256 + loc * 16 + n] : 0.0f;
            }
            dst[j] = (_Float16)(alpha * v);
        }
    }
}

// ================= fused conv (f16 MFMA) + replicated slot-map build =================
// ROUND-7: exact round-0 structure (best measured: 46us conv / 123us total) —
// contiguous per-edge stores, barriers, global bfrag. ONLY change: the slot-map
// atomic goes to one of NREP=4 replicated counter arrays (r = blockIdx&3), and
// pos slots are replica-ranged. Theory: 200k returning atomics into ~390 cache
// lines (~512 same-line RMWs each) serialize at the L2/fabric and set the
// structure-independent ~46us floor; 4x more lines -> ~4x shorter queues.
__global__ __launch_bounds__(256) void k_conv(
        const float* __restrict__ node_attr,
        const int*   __restrict__ edge_index,
        const float* __restrict__ edge_attr,
        const float* __restrict__ edge_sh,
        const float* __restrict__ w1,
        const float* __restrict__ b1,
        const f16x8* __restrict__ bfrag,
        int* __restrict__ cnt,
        int* __restrict__ pos,
        _Float16* __restrict__ edge_out)
{
    const int t = threadIdx.x;
    __shared__ float  sh_h[64][17];                 // 4352 B
    __shared__ float4 sh_y[64];                     // 1024 B
    __shared__ _Float16 sh_s[6][64][24];            // 18432 B (48 B rows)

    const int ebase = blockIdx.x * 64;
    const float inv_sqrt3 = 0.57735026918962576f;

    // ---- slot-map insert (fire-and-forget: nothing in-kernel consumes it)
    if (t < 64) {
        const int e2 = ebase + t;
        const int d = edge_index[E_TOTAL + e2];
        const int r = blockIdx.x & (NREP - 1);
        int slot = atomicAdd(&cnt[r * NNODES + d], 1);
        if (slot >= RSLOT) slot = RSLOT - 1;        // memory-safety clamp (never hit)
        pos[d * PAD + r * RSLOT + slot] = e2;
    }

    // ---- phase 1a: h = silu(edge_attr @ w1 + b1)
    {
        const int e_loc = t & 63, kq = t >> 6;
        const int e = ebase + e_loc;
        const float* ea = edge_attr + (size_t)e * 16;
        float ear[16];
        #pragma unroll
        for (int dq = 0; dq < 4; ++dq) {
            float4 v = *(const float4*)(ea + dq * 4);
            ear[dq * 4 + 0] = v.x; ear[dq * 4 + 1] = v.y;
            ear[dq * 4 + 2] = v.z; ear[dq * 4 + 3] = v.w;
        }
        float4 acc = *(const float4*)(b1 + kq * 4);
        #pragma unroll
        for (int d = 0; d < 16; ++d) {
            float4 wr = *(const float4*)(w1 + d * 16 + kq * 4);
            acc.x += ear[d] * wr.x; acc.y += ear[d] * wr.y;
            acc.z += ear[d] * wr.z; acc.w += ear[d] * wr.w;
        }
        sh_h[e_loc][kq * 4 + 0] = acc.x / (1.0f + __expf(-acc.x));
        sh_h[e_loc][kq * 4 + 1] = acc.y / (1.0f + __expf(-acc.y));
        sh_h[e_loc][kq * 4 + 2] = acc.z / (1.0f + __expf(-acc.z));
        sh_h[e_loc][kq * 4 + 3] = acc.w / (1.0f + __expf(-acc.w));
    }

    // ---- phase 1b: stage s-vectors (f16) + y
    {
        const int e_loc = (t & 15) + ((t >> 6) << 4);
        const int pp = (t >> 4) & 3;
        const int u0 = pp * 4;
        const int e = ebase + e_loc;
        const int src = edge_index[e];
        const float4 yv = *(const float4*)(edge_sh + (size_t)e * 4);
        const float* xp = node_attr + (size_t)src * 64;
        float4 x0v = *(const float4*)(xp + u0);
        float x1v[4][3];
        #pragma unroll
        for (int q = 0; q < 4; ++q)
            #pragma unroll
            for (int i = 0; i < 3; ++i)
                x1v[q][i] = xp[16 + (u0 + q) * 3 + i];
        const float* x0p = &x0v.x;
        f16x4 s0h, s1h, x0h, ah, bh, ch;
        #pragma unroll
        for (int q = 0; q < 4; ++q) {
            s0h[q] = (_Float16)(x0p[q] * yv.x);
            s1h[q] = (_Float16)(inv_sqrt3 * (x1v[q][0] * yv.y + x1v[q][1] * yv.z + x1v[q][2] * yv.w));
            x0h[q] = (_Float16)x0p[q];
            ah[q]  = (_Float16)x1v[q][0];
            bh[q]  = (_Float16)x1v[q][1];
            ch[q]  = (_Float16)x1v[q][2];
        }
        *(f16x4*)&sh_s[0][e_loc][u0] = s0h;
        *(f16x4*)&sh_s[1][e_loc][u0] = s1h;
        *(f16x4*)&sh_s[2][e_loc][u0] = x0h;
        *(f16x4*)&sh_s[3][e_loc][u0] = ah;
        *(f16x4*)&sh_s[4][e_loc][u0] = bh;
        *(f16x4*)&sh_s[5][e_loc][u0] = ch;
        if (pp == 0) sh_y[e_loc] = yv;
    }
    __syncthreads();

    // ---- phase 2: MFMA K-loop
    const int lane = t & 63, wv = t >> 6;
    const int m = lane & 15, quad = lane >> 4;
    const int e_loc = wv * 16 + m;
    const int qh = quad >> 1, ql = quad & 1;

    AF svh[6];
    #pragma unroll
    for (int b = 0; b < 6; ++b)
        svh[b].f = *(const f16x8*)&sh_s[b][e_loc][ql * 8];
    float hreg[8];
    #pragma unroll
    for (int kb = 0; kb < 8; ++kb) hreg[kb] = sh_h[e_loc][2 * kb + qh];

    f32x4 acc0  = {0.f, 0.f, 0.f, 0.f};
    f32x4 acc2  = {0.f, 0.f, 0.f, 0.f};
    f32x4 acc3a = {0.f, 0.f, 0.f, 0.f};
    f32x4 acc3b = {0.f, 0.f, 0.f, 0.f};
    f32x4 acc3c = {0.f, 0.f, 0.f, 0.f};

    for (int kb = 0; kb < 9; ++kb) {
        const f16x8 B0 = bfrag[(0 * 9 + kb) * 64 + lane];
        const f16x8 B1 = bfrag[(1 * 9 + kb) * 64 + lane];
        const f16x8 B2 = bfrag[(2 * 9 + kb) * 64 + lane];
        const f16x8 B3 = bfrag[(3 * 9 + kb) * 64 + lane];
        const float selF = (kb < 8) ? hreg[kb] : ((quad < 2) ? 1.0f : 0.0f);
        const _Float16 sh1 = (_Float16)selF;
        const f16x2 sel2 = (f16x2){sh1, sh1};
        AF A[6];
        #pragma unroll
        for (int b = 0; b < 6; ++b)
            #pragma unroll
            for (int p = 0; p < 4; ++p)
                A[b].h2[p] = sel2 * svh[b].h2[p];    // v_pk_mul_f16
        acc0  = __builtin_amdgcn_mfma_f32_16x16x32_f16(A[0].f, B0, acc0, 0, 0, 0);
        acc0  = __builtin_amdgcn_mfma_f32_16x16x32_f16(A[1].f, B1, acc0, 0, 0, 0);
        acc2  = __builtin_amdgcn_mfma_f32_16x16x32_f16(A[2].f, B2, acc2, 0, 0, 0);
        acc3a = __builtin_amdgcn_mfma_f32_16x16x32_f16(A[3].f, B3, acc3a, 0, 0, 0);
        acc3b = __builtin_amdgcn_mfma_f32_16x16x32_f16(A[4].f, B3, acc3b, 0, 0, 0);
        acc3c = __builtin_amdgcn_mfma_f32_16x16x32_f16(A[5].f, B3, acc3c, 0, 0, 0);
    }

    // ---- epilogue: contiguous f16 lane-chunked rows (2 KB per wave)
    #pragma unroll
    for (int r = 0; r < 4; ++r) {
        const int el = wv * 16 + quad * 4 + r;
        const float4 yv = sh_y[el];
        const float t2v = acc2[r];
        const float o0 = acc0[r];
        const float oa = yv.y * t2v + yv.x * acc3a[r];
        const float ob = yv.z * t2v + yv.x * acc3b[r];
        const float oc = yv.w * t2v + yv.x * acc3c[r];
        f16x4 pk = {(_Float16)o0, (_Float16)oa, (_Float16)ob, (_Float16)oc};
        *(f16x4*)(edge_out + (size_t)(ebase + el) * 64 + m * 4) = pk;
    }
}

// ================= gather (segment mean): replica-ranged slot walk =================
// One wave per node. Lane l pre-loads pos[n*PAD + l] and pos[n*PAD + 64 + l]
// (coalesced); indices broadcast via __shfl; row-reads are INDEPENDENT,
// 4-way unrolled for memory-level parallelism. Four replica ranges walked
// in sequence (all unrolled, loads overlap).
__global__ __launch_bounds__(256) void k_gather(const _Float16* __restrict__ edge_out,
                                                const int* __restrict__ cnt,
                                                const int* __restrict__ pos,
                                                float* __restrict__ out) {
    const int t = threadIdx.x;
    const int lane = t & 63;
    const int n = blockIdx.x * 4 + (t >> 6);
    // in-row permutation: elem<16 -> row[elem*4]; elem=16+w*3+i -> row[w*4+1+i]
    int pe;
    if (lane < 16) pe = lane * 4;
    else { const int idx = lane - 16; const int w = idx / 3; pe = w * 4 + 1 + (idx - w * 3); }
    int c0 = cnt[0 * NNODES + n]; if (c0 > RSLOT) c0 = RSLOT;
    int c1 = cnt[1 * NNODES + n]; if (c1 > RSLOT) c1 = RSLOT;
    int c2 = cnt[2 * NNODES + n]; if (c2 > RSLOT) c2 = RSLOT;
    int c3 = cnt[3 * NNODES + n]; if (c3 > RSLOT) c3 = RSLOT;
    const int p0 = pos[n * PAD + lane];         // slots   0..63  (replicas 0,1)
    const int p1 = pos[n * PAD + 64 + lane];    // slots  64..127 (replicas 2,3)
    float a0 = 0.f, a1 = 0.f, a2 = 0.f, a3 = 0.f;

#define GATHER_RANGE(P, B, CR)                                          \
    {                                                                   \
        int j = 0;                                                      \
        for (; j + 4 <= (CR); j += 4) {                                 \
            const int r0i = __shfl((P), (B) + j + 0);                   \
            const int r1i = __shfl((P), (B) + j + 1);                   \
            const int r2i = __shfl((P), (B) + j + 2);                   \
            const int r3i = __shfl((P), (B) + j + 3);                   \
            a0 += (float)edge_out[(size_t)r0i * 64 + pe];               \
            a1 += (float)edge_out[(size_t)r1i * 64 + pe];               \
            a2 += (float)edge_out[(size_t)r2i * 64 + pe];               \
            a3 += (float)edge_out[(size_t)r3i * 64 + pe];               \
        }                                                               \
        for (; j < (CR); ++j) {                                         \
            const int ri = __shfl((P), (B) + j);                        \
            a0 += (float)edge_out[(size_t)ri * 64 + pe];                \
        }                                                               \
    }

    GATHER_RANGE(p0, 0,     c0)
    GATHER_RANGE(p0, RSLOT, c1)
    GATHER_RANGE(p1, 0,     c2)
    GATHER_RANGE(p1, RSLOT, c3)
#undef GATHER_RANGE

    const int c = c0 + c1 + c2 + c3;
    const float acc = (a0 + a1) + (a2 + a3);
    out[n * 64 + lane] = acc / (c > 0 ? (float)c : 1.0f);
}

// ================= fallback path (round-1 atomic fp32, proven) =================
__global__ void k_zero_f(float* __restrict__ out, float* __restrict__ counts) {
    int i = blockIdx.x * 256 + threadIdx.x;
    if (i < OUT_ELEM) out[i] = 0.0f;
    if (i < NNODES)   counts[i] = 0.0f;
}

#define EPB 80
#define NE  8
__global__ __launch_bounds__(256) void k_conv_atomic(
        const float* __restrict__ node_attr,
        const int*   __restrict__ edge_index,
        const float* __restrict__ edge_attr,
        const float* __restrict__ edge_sh,
        const float* __restrict__ w1,
        const float* __restrict__ b1,
        const float* __restrict__ w2,
        const float* __restrict__ b2,
        float* __restrict__ out,
        float* __restrict__ counts)
{
    const int thr   = threadIdx.x;
    const int lane  = thr & 63;
    const int wv    = thr >> 6;
    const int u     = lane >> 2;
    const int wbase = (lane & 3) * 4;

    float4 w2r[16];
    #pragma unroll
    for (int k = 0; k < 16; ++k)
        w2r[k] = *(const float4*)(w2 + k * 1024 + thr * 4);
    const float4 b2r = *(const float4*)(b2 + thr * 4);

    __shared__ __align__(16) float sh_h[NE][16];
    __shared__ float sh_s0[NE][16];
    __shared__ float sh_s1[NE][16];
    __shared__ float sh_x0[NE][16];
    __shared__ float sh_x1[NE][16][3];
    __shared__ float sh_y0[NE];
    __shared__ float sh_y1[NE][3];
    __shared__ int   sh_dst[NE];

    const float alpha     = 0.17677669529663687f;
    const float inv_sqrt3 = 0.57735026918962576f;
    const int e0 = blockIdx.x * EPB;

    for (int batch = 0; batch < EPB / NE; ++batch) {
        const int ebase = e0 + batch * NE;
        if (thr < 128) {
            const int le = thr >> 4, k = thr & 15;
            const int e = ebase + le;
            float acc = b1[k];
            const float* ea = edge_attr + (size_t)e * 16;
            #pragma unroll
            for (int d = 0; d < 16; ++d) acc += ea[d] * w1[d * 16 + k];
            sh_h[le][k] = acc / (1.0f + __expf(-acc));
            if (k == 0) sh_dst[le] = edge_index[E_TOTAL + e];
        } else {
            const int le = (thr - 128) >> 4, uu = thr & 15;
            const int e = ebase + le;
            const int src = edge_index[e];
            const float y0  = edge_sh[e * 4 + 0];
            const float y1a = edge_sh[e * 4 + 1];
            const float y1b = edge_sh[e * 4 + 2];
            const float y1c = edge_sh[e * 4 + 3];
            const float* xp = node_attr + (size_t)src * 64;
            const float x0v = xp[uu];
            const float xa = xp[16 + uu * 3 + 0];
            const float xb = xp[16 + uu * 3 + 1];
            const float xc = xp[16 + uu * 3 + 2];
            sh_x0[le][uu] = x0v;
            sh_x1[le][uu][0] = xa; sh_x1[le][uu][1] = xb; sh_x1[le][uu][2] = xc;
            sh_s0[le][uu] = x0v * y0;
            sh_s1[le][uu] = inv_sqrt3 * (xa * y1a + xb * y1b + xc * y1c);
            if (uu == 0) {
                sh_y0[le] = y0;
                sh_y1[le][0] = y1a; sh_y1[le][1] = y1b; sh_y1[le][2] = y1c;
            }
        }
        __syncthreads();

        for (int le = 0; le < NE; ++le) {
            float W0 = b2r.x, W1 = b2r.y, W2c = b2r.z, W3c = b2r.w;
            const float4* hv = (const float4*)sh_h[le];
            #pragma unroll
            for (int kk = 0; kk < 4; ++kk) {
                const float4 h4 = hv[kk];
                const int kb = kk * 4;
                W0  += h4.x * w2r[kb + 0].x; W1  += h4.x * w2r[kb + 0].y;
                W2c += h4.x * w2r[kb + 0].z; W3c += h4.x * w2r[kb + 0].w;
                W0  += h4.y * w2r[kb + 1].x; W1  += h4.y * w2r[kb + 1].y;
                W2c += h4.y * w2r[kb + 1].z; W3c += h4.y * w2r[kb + 1].w;
                W0  += h4.z * w2r[kb + 2].x; W1  += h4.z * w2r[kb + 2].y;
                W2c += h4.z * w2r[kb + 2].z; W3c += h4.z * w2r[kb + 2].w;
                W0  += h4.w * w2r[kb + 3].x; W1  += h4.w * w2r[kb + 3].y;
                W2c += h4.w * w2r[kb + 3].z; W3c += h4.w * w2r[kb + 3].w;
            }
            const int dst = sh_dst[le];
            float* op = out + (size_t)dst * 64;
            if (wv == 0 || wv == 1) {
                const float s = (wv == 0) ? sh_s0[le][u] : sh_s1[le][u];
                float v0 = s * W0, v1 = s * W1, v2 = s * W2c, v3 = s * W3c;
                #pragma unroll
                for (int off = 4; off <= 32; off <<= 1) {
                    v0 += __shfl_xor(v0, off); v1 += __shfl_xor(v1, off);
                    v2 += __shfl_xor(v2, off); v3 += __shfl_xor(v3, off);
                }
                if (lane < 4) {
                    atomicAdd(op + wbase + 0, alpha * v0);
                    atomicAdd(op + wbase + 1, alpha * v1);
                    atomicAdd(op + wbase + 2, alpha * v2);
                    atomicAdd(op + wbase + 3, alpha * v3);
                    if (wv == 0 && lane == 0) atomicAdd(&counts[dst], 1.0f);
                }
            } else if (wv == 2) {
                const float s = sh_x0[le][u];
                float v0 = s * W0, v1 = s * W1, v2 = s * W2c, v3 = s * W3c;
                #pragma unroll
                for (int off = 4; off <= 32; off <<= 1) {
                    v0 += __shfl_xor(v0, off); v1 += __shfl_xor(v1, off);
                    v2 += __shfl_xor(v2, off); v3 += __shfl_xor(v3, off);
                }
                if (lane < 4) {
                    const float ya = alpha * sh_y1[le][0];
                    const float yb = alpha * sh_y1[le][1];
                    const float yc = alpha * sh_y1[le][2];
                    float vv[4] = {v0, v1, v2, v3};
                    #pragma unroll
                    for (int q = 0; q < 4; ++q) {
                        float* qp = op + 16 + (wbase + q) * 3;
                        atomicAdd(qp + 0, vv[q] * ya);
                        atomicAdd(qp + 1, vv[q] * yb);
                        atomicAdd(qp + 2, vv[q] * yc);
                    }
                }
            } else {
                const float ay0 = alpha * sh_y0[le];
                #pragma unroll
                for (int i = 0; i < 3; ++i) {
                    const float s = sh_x1[le][u][i];
                    float v0 = s * W0, v1 = s * W1, v2 = s * W2c, v3 = s * W3c;
                    #pragma unroll
                    for (int off = 4; off <= 32; off <<= 1) {
                        v0 += __shfl_xor(v0, off); v1 += __shfl_xor(v1, off);
                        v2 += __shfl_xor(v2, off); v3 += __shfl_xor(v3, off);
                    }
                    if (lane < 4) {
                        atomicAdd(op + 16 + (wbase + 0) * 3 + i, ay0 * v0);
                        atomicAdd(op + 16 + (wbase + 1) * 3 + i, ay0 * v1);
                        atomicAdd(op + 16 + (wbase + 2) * 3 + i, ay0 * v2);
                        atomicAdd(op + 16 + (wbase + 3) * 3 + i, ay0 * v3);
                    }
                }
            }
        }
        __syncthreads();
    }
}

__global__ void k_div(float* __restrict__ out, const float* __restrict__ counts) {
    int i = blockIdx.x * 256 + threadIdx.x;
    if (i < OUT_ELEM) {
        float c = counts[i >> 6];
        out[i] *= 1.0f / fmaxf(c, 1.0f);
    }
}

// ================= launch =================
extern "C" void kernel_launch(void* const* d_in, const int* in_sizes, int n_in,
                              void* d_out, int out_size, void* d_ws, size_t ws_size,
                              hipStream_t stream) {
    const float* node_attr  = (const float*)d_in[0];
    const int*   edge_index = (const int*)d_in[1];
    const float* edge_attr  = (const float*)d_in[2];
    const float* edge_sh    = (const float*)d_in[3];
    const float* w1         = (const float*)d_in[4];
    const float* b1         = (const float*)d_in[5];
    const float* w2         = (const float*)d_in[6];
    const float* b2         = (const float*)d_in[7];
    float* out = (float*)d_out;

    if (ws_size >= WS_NEEDED) {
        char* ws = (char*)d_ws;
        _Float16* edge_out = (_Float16*)ws;
        int*      cnt      = (int*)(ws + OFF_CNT);
        int*      pos      = (int*)(ws + OFF_POS);
        _Float16* bfrag    = (_Float16*)(ws + OFF_BFRAG);

        k_prep<<<(NREP * NNODES + 255) / 256, 256, 0, stream>>>(w2, b2, cnt, bfrag);
        k_conv<<<NTILE, 256, 0, stream>>>(
            node_attr, edge_index, edge_attr, edge_sh, w1, b1,
            (const f16x8*)bfrag, cnt, pos, edge_out);
        k_gather<<<NNODES / 4, 256, 0, stream>>>(edge_out, cnt, pos, out);
    } else {
        float* counts = (float*)d_ws;
        k_zero_f<<<(OUT_ELEM + 255) / 256, 256, 0, stream>>>(out, counts);
        k_conv_atomic<<<E_TOTAL / EPB, 256, 0, stream>>>(
            node_attr, edge_index, edge_attr, edge_sh, w1, b1, w2, b2, out, counts);
        k_div<<<(OUT_ELEM + 255) / 256, 256, 0, stream>>>(out, counts);
    }
}